// Round 1
// baseline (32925.168 us; speedup 1.0000x reference)
//
#include <hip/hip_runtime.h>
#include <stdint.h>

typedef unsigned int uint;
typedef unsigned short ushort_t;
typedef __attribute__((ext_vector_type(8))) short short8;
typedef __attribute__((ext_vector_type(4))) float f32x4;

#define AS1 __attribute__((address_space(1)))
#define AS3 __attribute__((address_space(3)))

__device__ __forceinline__ unsigned short f2bf(float f) {
  uint u = __float_as_uint(f);
  u += 0x7fffu + ((u >> 16) & 1u);
  return (unsigned short)(u >> 16);
}
__device__ __forceinline__ float bfl(unsigned short s) {
  return __uint_as_float(((uint)s) << 16);
}

// ---------------- build kernels ----------------

// A[dir][m=t*8+b][e] = bf16(x or x_rev), 2 x 4096 x 1024
__global__ __launch_bounds__(256) void k_build_A(const float* __restrict__ x,
                                                 const int* __restrict__ lengths,
                                                 unsigned short* __restrict__ A) {
  int idx = blockIdx.x * 256 + threadIdx.x;   // float4 units, 2*1Mi total
  int dir = idx >> 20;
  int r = idx & 1048575;
  int m = r >> 8;
  int e4 = r & 255;
  int t = m >> 3, b = m & 7;
  int st = t;
  if (dir) { int len = lengths[b]; st = (t < len) ? (len - 1 - t) : t; }
  float4 v = *(const float4*)&x[((size_t)b * 512 + st) * 1024 + e4 * 4];
  ushort4 o;
  o.x = f2bf(v.x); o.y = f2bf(v.y); o.z = f2bf(v.z); o.w = f2bf(v.w);
  *(ushort4*)&A[(size_t)dir * 4194304 + (size_t)m * 1024 + e4 * 4] = o;
}

// Wp[dir][j][e] = bf16(W_ih)
__global__ __launch_bounds__(256) void k_cast_wih(const float* __restrict__ Wf,
                                                  const float* __restrict__ Wb,
                                                  unsigned short* __restrict__ Wp) {
  int idx = blockIdx.x * 256 + threadIdx.x;
  int dir = idx >> 20;
  int r = idx & 1048575;
  const float* src = dir ? Wb : Wf;
  float4 v = *(const float4*)&src[(size_t)r * 4];
  ushort4 o;
  o.x = f2bf(v.x); o.y = f2bf(v.y); o.z = f2bf(v.z); o.w = f2bf(v.w);
  *(ushort4*)&Wp[(size_t)dir * 4194304 + (size_t)r * 4] = o;
}

// Wt4[dir][h4][j][u] = bf16(W_hh[j][h4*4+u])   (h4<256, j<4096)
__global__ __launch_bounds__(256) void k_build_wt(const float* __restrict__ Wf,
                                                  const float* __restrict__ Wb,
                                                  unsigned short* __restrict__ Wt4) {
  int idx = blockIdx.x * 256 + threadIdx.x;
  int dir = idx >> 20;
  int r = idx & 1048575;
  int j = r >> 8;
  int h4 = r & 255;
  const float* src = dir ? Wb : Wf;
  float4 v = *(const float4*)&src[(size_t)j * 1024 + h4 * 4];
  ushort4 o;
  o.x = f2bf(v.x); o.y = f2bf(v.y); o.z = f2bf(v.z); o.w = f2bf(v.w);
  *(ushort4*)&Wt4[(size_t)dir * 4194304 + ((size_t)h4 * 4096 + j) * 4] = o;
}

// WET[e][k] = W_emit[k][e]  (fp32)
__global__ __launch_bounds__(256) void k_build_wet(const float* __restrict__ We,
                                                   float* __restrict__ WET) {
  int idx = blockIdx.x * 256 + threadIdx.x;  // 32768
  int e = idx >> 4, k = idx & 15;
  WET[(size_t)e * 16 + k] = We[(size_t)k * 2048 + e];
}

// ---------------- projection GEMM (bf16 MFMA): P[dir][m][j] = A @ W_ih^T + b ----------------
__global__ __launch_bounds__(256) void k_proj(const unsigned short* __restrict__ A,
                                              const unsigned short* __restrict__ Wp,
                                              const float* __restrict__ bfv,
                                              const float* __restrict__ bbv,
                                              unsigned short* __restrict__ P) {
  const int dir = blockIdx.z;
  const unsigned short* Ad = A + (size_t)dir * 4194304;
  const unsigned short* Wd = Wp + (size_t)dir * 4194304;
  const float* bias = dir ? bbv : bfv;
  unsigned short* Pd = P + (size_t)dir * 16777216;
  const int bm = blockIdx.x * 128;
  const int bn = blockIdx.y * 128;
  __shared__ unsigned short As[128 * 32];
  __shared__ unsigned short Bs[128 * 32];
  const int tid = threadIdx.x;
  const int w = tid >> 6, lane = tid & 63;
  const int wm = (w >> 1) * 64, wn = (w & 1) * 64;
  const int q = lane >> 4, rr = lane & 15;

  f32x4 acc[4][4];
#pragma unroll
  for (int i = 0; i < 4; ++i)
#pragma unroll
    for (int j = 0; j < 4; ++j) acc[i][j] = (f32x4){0.f, 0.f, 0.f, 0.f};

  for (int k0 = 0; k0 < 1024; k0 += 32) {
#pragma unroll
    for (int i = 0; i < 2; ++i) {
      int c = i * 256 + tid;
      int row = c >> 2, col = (c & 3) * 8;
      const unsigned short* ga = Ad + (size_t)(bm + row) * 1024 + k0 + col;
      const unsigned short* gb = Wd + (size_t)(bn + row) * 1024 + k0 + col;
      __builtin_amdgcn_global_load_lds((const AS1 void*)ga,
                                       (AS3 void*)&As[(i * 256 + w * 64) * 8], 16, 0, 0);
      __builtin_amdgcn_global_load_lds((const AS1 void*)gb,
                                       (AS3 void*)&Bs[(i * 256 + w * 64) * 8], 16, 0, 0);
    }
    __syncthreads();
    short8 av[4], bv[4];
#pragma unroll
    for (int i = 0; i < 4; ++i)
      av[i] = *(const short8*)&As[(wm + i * 16 + rr) * 32 + q * 8];
#pragma unroll
    for (int j = 0; j < 4; ++j)
      bv[j] = *(const short8*)&Bs[(wn + j * 16 + rr) * 32 + q * 8];
#pragma unroll
    for (int i = 0; i < 4; ++i)
#pragma unroll
      for (int j = 0; j < 4; ++j)
        acc[i][j] = __builtin_amdgcn_mfma_f32_16x16x32_bf16(av[i], bv[j], acc[i][j], 0, 0, 0);
    __syncthreads();
  }
#pragma unroll
  for (int i = 0; i < 4; ++i)
#pragma unroll
    for (int j = 0; j < 4; ++j)
#pragma unroll
      for (int reg = 0; reg < 4; ++reg) {
        int row = wm + i * 16 + q * 4 + reg;
        int col = wn + j * 16 + rr;
        float vv = acc[i][j][reg] + bias[bn + col];
        Pd[(size_t)(bm + row) * 4096 + bn + col] = f2bf(vv);
      }
}

// ---------------- LSTM step (both directions), one launch per t ----------------
// grid 256: dir = bid&1, grp = bid>>1 (8 hidden units x 4 gates x 8 batches per block)
__global__ __launch_bounds__(256) void k_step(int t,
    const unsigned short* __restrict__ Wt4, const unsigned short* __restrict__ P,
    const int* __restrict__ lengths,
    float* __restrict__ h_state, float* __restrict__ c_state,
    float* __restrict__ h_seq) {
  __shared__ float hv[8 * 1036];   // pad 1036: banks spread, 16B aligned
  __shared__ float gates[256];
  const int bid = blockIdx.x;
  const int dir = bid & 1;
  const int grp = bid >> 1;
  const int m0 = grp * 8;
  const int tid = threadIdx.x;

  if (t > 0) {
    const float4* hs4 = (const float4*)(h_state + (size_t)dir * 8192);
#pragma unroll
    for (int i = 0; i < 8; ++i) {
      int idx = tid + i * 256;        // float4 index, 2048 total
      int b = idx >> 8, h4 = idx & 255;
      float4 v = hs4[idx];
      *(float4*)&hv[b * 1036 + h4 * 4] = v;
    }
  }
  __syncthreads();

  const int b = tid & 7;
  const int rl = tid >> 3;
  const int gate = rl >> 3;
  const int ml = rl & 7;
  const int j = gate * 1024 + m0 + ml;

  float acc = 0.f;
  if (t > 0) {
    const unsigned short* wp = Wt4 + (size_t)dir * 4194304 + (size_t)j * 4;
    const float* hb_ = &hv[b * 1036];
#pragma unroll 16
    for (int h4 = 0; h4 < 256; ++h4) {
      uint2 wq = *(const uint2*)(wp + (size_t)h4 * 16384);
      float4 hh = *(const float4*)(hb_ + h4 * 4);
      acc += __uint_as_float((wq.x & 0xffffu) << 16) * hh.x
           + __uint_as_float(wq.x & 0xffff0000u) * hh.y
           + __uint_as_float((wq.y & 0xffffu) << 16) * hh.z
           + __uint_as_float(wq.y & 0xffff0000u) * hh.w;
    }
  }
  float pv = bfl(P[((size_t)(dir * 512 + t) * 8 + b) * 4096 + j]);
  gates[gate * 64 + ml * 8 + b] = acc + pv;
  __syncthreads();

  if (tid < 64) {
    int b2 = tid & 7, m2 = tid >> 3;
    int len = lengths[b2];
    if (t < len) {
      float gi = gates[m2 * 8 + b2];
      float gf = gates[64 + m2 * 8 + b2];
      float gg = gates[128 + m2 * 8 + b2];
      float go = gates[192 + m2 * 8 + b2];
      int m = m0 + m2;
      size_t sidx = (size_t)dir * 8192 + (size_t)b2 * 1024 + m;
      float c_old = (t == 0) ? 0.f : c_state[sidx];
      float si = 1.f / (1.f + __expf(-gi));
      float sf = 1.f / (1.f + __expf(-gf));
      float so = 1.f / (1.f + __expf(-go));
      float tg = tanhf(gg);
      float cn = sf * c_old + si * tg;
      float hn = so * tanhf(cn);
      c_state[sidx] = cn;
      h_state[sidx] = hn;
      h_seq[((size_t)(dir * 512 + t) * 8 + b2) * 1024 + m] = hn;
    }
  }
}

// ---------------- emissions: emit[t*8+b][k] = [hf, hb(rev)] @ W_emit^T + b_emit ----------------
__global__ __launch_bounds__(64) void k_emit(const float* __restrict__ h_seq,
    const float* __restrict__ WET, const float* __restrict__ b_emit,
    const int* __restrict__ lengths, float* __restrict__ emit) {
  __shared__ float hl[4][2048];
  const int tid = threadIdx.x;
  const int p0 = blockIdx.x * 4;
  for (int i = 0; i < 32; ++i) {
    int idx = tid + i * 64;          // float4 index 0..2047
    int pl = idx >> 9;
    int r = idx & 511;
    int p = p0 + pl;
    int t = p >> 3, b = p & 7;
    int len = lengths[b];
    float4 v = make_float4(0.f, 0.f, 0.f, 0.f);
    if (t < len) {
      if (r < 256) {
        v = *(const float4*)&h_seq[((size_t)t * 8 + b) * 1024 + r * 4];
      } else {
        int tr = len - 1 - t;
        v = *(const float4*)&h_seq[((size_t)(512 + tr) * 8 + b) * 1024 + (r - 256) * 4];
      }
    }
    *(float4*)&hl[pl][r * 4] = v;
  }
  __syncthreads();
  const int k = tid & 15, pl = tid >> 4;
  const int p = p0 + pl;
  const int t = p >> 3, b = p & 7;
  const int len = lengths[b];
  float acc = 0.f;
  if (t < len) {
    const float* hrow = hl[pl];
#pragma unroll 4
    for (int e4 = 0; e4 < 512; ++e4) {
      float4 h4 = *(const float4*)&hrow[e4 * 4];
      acc += h4.x * WET[(e4 * 4 + 0) * 16 + k]
           + h4.y * WET[(e4 * 4 + 1) * 16 + k]
           + h4.z * WET[(e4 * 4 + 2) * 16 + k]
           + h4.w * WET[(e4 * 4 + 3) * 16 + k];
    }
    acc += b_emit[k];
  }
  emit[(size_t)p * 16 + k] = (t < len) ? acc : 0.f;
}

// ---------------- CRF: gold score + forward algorithm, out[b] = logZ - total ----------------
__global__ __launch_bounds__(128) void k_crf(const float* __restrict__ emit,
    const int* __restrict__ tags, const int* __restrict__ lengths,
    const float* __restrict__ trans, float* __restrict__ out) {
  __shared__ float d_lds[8][17];
  __shared__ float tot[8][17];
  __shared__ float totb[8];
  const int tid = threadIdx.x;
  const int b = tid >> 4, k = tid & 15;
  const int len = lengths[b];

  float part = 0.f;
  for (int t = k; t < 512; t += 16) {
    if (t < len) {
      int tg = tags[b * 512 + t];
      part += emit[((size_t)t * 8 + b) * 16 + tg];
      if (t >= 1) part += trans[tags[b * 512 + t - 1] * 16 + tg];
    }
  }
  tot[b][k] = part;

  float trc[16];
#pragma unroll
  for (int i = 0; i < 16; ++i) trc[i] = trans[i * 16 + k];
  d_lds[b][k] = emit[b * 16 + k];
  __syncthreads();
  if (k == 0) {
    float s = 0.f;
    for (int i = 0; i < 16; ++i) s += tot[b][i];
    totb[b] = s;
  }
  __syncthreads();

  for (int t = 1; t < 512; ++t) {
    float nd = 0.f;
    bool upd = (t < len);
    if (upd) {
      float mx = -3.0e38f;
      float v[16];
#pragma unroll
      for (int i = 0; i < 16; ++i) { v[i] = d_lds[b][i] + trc[i]; mx = fmaxf(mx, v[i]); }
      float s = 0.f;
#pragma unroll
      for (int i = 0; i < 16; ++i) s += __expf(v[i] - mx);
      nd = mx + __logf(s) + emit[((size_t)t * 8 + b) * 16 + k];
    }
    __syncthreads();
    if (upd) d_lds[b][k] = nd;
    __syncthreads();
  }

  if (k == 0) {
    float mx = -3.0e38f;
    for (int i = 0; i < 16; ++i) mx = fmaxf(mx, d_lds[b][i]);
    float s = 0.f;
    for (int i = 0; i < 16; ++i) s += __expf(d_lds[b][i] - mx);
    out[b] = (mx + __logf(s)) - totb[b];
  }
}

extern "C" void kernel_launch(void* const* d_in, const int* in_sizes, int n_in,
                              void* d_out, int out_size, void* d_ws, size_t ws_size,
                              hipStream_t stream) {
  const float* x       = (const float*)d_in[0];
  const int*   tags    = (const int*)d_in[1];
  const int*   lengths = (const int*)d_in[2];
  const float* W_ih_f  = (const float*)d_in[3];
  const float* W_hh_f  = (const float*)d_in[4];
  const float* b_f     = (const float*)d_in[5];
  const float* W_ih_b  = (const float*)d_in[6];
  const float* W_hh_b  = (const float*)d_in[7];
  const float* b_b     = (const float*)d_in[8];
  const float* W_emit  = (const float*)d_in[9];
  const float* b_emit  = (const float*)d_in[10];
  const float* trans   = (const float*)d_in[11];
  float* out = (float*)d_out;
  (void)in_sizes; (void)n_in; (void)out_size; (void)ws_size;

  char* ws = (char*)d_ws;
  unsigned short* A    = (unsigned short*)ws; ws += 16777216;   // 2 x 4096 x 1024 bf16
  unsigned short* Wp   = (unsigned short*)ws; ws += 16777216;   // 2 x 4096 x 1024 bf16
  unsigned short* Wt4  = (unsigned short*)ws; ws += 16777216;   // 2 x 256 x 4096 x 4 bf16
  unsigned short* P    = (unsigned short*)ws; ws += 67108864;   // 2 x 4096 x 4096 bf16
  float* h_seq = (float*)ws; ws += 33554432;                    // 2 x 512 x 8 x 1024 f32
  float* h_st  = (float*)ws; ws += 65536;
  float* c_st  = (float*)ws; ws += 65536;
  float* emit  = (float*)ws; ws += 262144;
  float* WET   = (float*)ws; ws += 131072;

  k_build_A<<<8192, 256, 0, stream>>>(x, lengths, A);
  k_cast_wih<<<8192, 256, 0, stream>>>(W_ih_f, W_ih_b, Wp);
  k_build_wt<<<8192, 256, 0, stream>>>(W_hh_f, W_hh_b, Wt4);
  k_build_wet<<<128, 256, 0, stream>>>(W_emit, WET);
  k_proj<<<dim3(32, 32, 2), 256, 0, stream>>>(A, Wp, b_f, b_b, P);
  for (int t = 0; t < 512; ++t)
    k_step<<<256, 256, 0, stream>>>(t, Wt4, P, lengths, h_st, c_st, h_seq);
  k_emit<<<1024, 64, 0, stream>>>(h_seq, WET, b_emit, lengths, emit);
  k_crf<<<1, 128, 0, stream>>>(emit, tags, lengths, trans, out);
}

// Round 2
// 19370.979 us; speedup vs baseline: 1.6997x; 1.6997x over previous
//
#include <hip/hip_runtime.h>
#include <hip/hip_cooperative_groups.h>
#include <stdint.h>

typedef unsigned int uint;
typedef __attribute__((ext_vector_type(8))) short short8;
typedef __attribute__((ext_vector_type(4))) float f32x4;

#define AS1 __attribute__((address_space(1)))
#define AS3 __attribute__((address_space(3)))

__device__ __forceinline__ unsigned short f2bf(float f) {
  uint u = __float_as_uint(f);
  u += 0x7fffu + ((u >> 16) & 1u);
  return (unsigned short)(u >> 16);
}
__device__ __forceinline__ float bfl(unsigned short s) {
  return __uint_as_float(((uint)s) << 16);
}

// ---------------- build kernels ----------------

// A[dir][m=t*8+b][e] = bf16(x or x_rev), 2 x 4096 x 1024
__global__ __launch_bounds__(256) void k_build_A(const float* __restrict__ x,
                                                 const int* __restrict__ lengths,
                                                 unsigned short* __restrict__ A) {
  int idx = blockIdx.x * 256 + threadIdx.x;   // float4 units, 2*1Mi total
  int dir = idx >> 20;
  int r = idx & 1048575;
  int m = r >> 8;
  int e4 = r & 255;
  int t = m >> 3, b = m & 7;
  int st = t;
  if (dir) { int len = lengths[b]; st = (t < len) ? (len - 1 - t) : t; }
  float4 v = *(const float4*)&x[((size_t)b * 512 + st) * 1024 + e4 * 4];
  ushort4 o;
  o.x = f2bf(v.x); o.y = f2bf(v.y); o.z = f2bf(v.z); o.w = f2bf(v.w);
  *(ushort4*)&A[(size_t)dir * 4194304 + (size_t)m * 1024 + e4 * 4] = o;
}

// Wp[dir][j][e] = bf16(W_ih)
__global__ __launch_bounds__(256) void k_cast_wih(const float* __restrict__ Wf,
                                                  const float* __restrict__ Wb,
                                                  unsigned short* __restrict__ Wp) {
  int idx = blockIdx.x * 256 + threadIdx.x;
  int dir = idx >> 20;
  int r = idx & 1048575;
  const float* src = dir ? Wb : Wf;
  float4 v = *(const float4*)&src[(size_t)r * 4];
  ushort4 o;
  o.x = f2bf(v.x); o.y = f2bf(v.y); o.z = f2bf(v.z); o.w = f2bf(v.w);
  *(ushort4*)&Wp[(size_t)dir * 4194304 + (size_t)r * 4] = o;
}

// WET[e][k] = W_emit[k][e]  (fp32)
__global__ __launch_bounds__(256) void k_build_wet(const float* __restrict__ We,
                                                   float* __restrict__ WET) {
  int idx = blockIdx.x * 256 + threadIdx.x;  // 32768
  int e = idx >> 4, k = idx & 15;
  WET[(size_t)e * 16 + k] = We[(size_t)k * 2048 + e];
}

// ---------------- projection GEMM (bf16 MFMA): P[dir][m][j] = A @ W_ih^T + b ----------------
__global__ __launch_bounds__(256) void k_proj(const unsigned short* __restrict__ A,
                                              const unsigned short* __restrict__ Wp,
                                              const float* __restrict__ bfv,
                                              const float* __restrict__ bbv,
                                              unsigned short* __restrict__ P) {
  const int dir = blockIdx.z;
  const unsigned short* Ad = A + (size_t)dir * 4194304;
  const unsigned short* Wd = Wp + (size_t)dir * 4194304;
  const float* bias = dir ? bbv : bfv;
  unsigned short* Pd = P + (size_t)dir * 16777216;
  const int bm = blockIdx.x * 128;
  const int bn = blockIdx.y * 128;
  __shared__ unsigned short As[128 * 32];
  __shared__ unsigned short Bs[128 * 32];
  const int tid = threadIdx.x;
  const int w = tid >> 6, lane = tid & 63;
  const int wm = (w >> 1) * 64, wn = (w & 1) * 64;
  const int q = lane >> 4, rr = lane & 15;

  f32x4 acc[4][4];
#pragma unroll
  for (int i = 0; i < 4; ++i)
#pragma unroll
    for (int j = 0; j < 4; ++j) acc[i][j] = (f32x4){0.f, 0.f, 0.f, 0.f};

  for (int k0 = 0; k0 < 1024; k0 += 32) {
#pragma unroll
    for (int i = 0; i < 2; ++i) {
      int c = i * 256 + tid;
      int row = c >> 2, col = (c & 3) * 8;
      const unsigned short* ga = Ad + (size_t)(bm + row) * 1024 + k0 + col;
      const unsigned short* gb = Wd + (size_t)(bn + row) * 1024 + k0 + col;
      __builtin_amdgcn_global_load_lds((const AS1 void*)ga,
                                       (AS3 void*)&As[(i * 256 + w * 64) * 8], 16, 0, 0);
      __builtin_amdgcn_global_load_lds((const AS1 void*)gb,
                                       (AS3 void*)&Bs[(i * 256 + w * 64) * 8], 16, 0, 0);
    }
    __syncthreads();
    short8 av[4], bv[4];
#pragma unroll
    for (int i = 0; i < 4; ++i)
      av[i] = *(const short8*)&As[(wm + i * 16 + rr) * 32 + q * 8];
#pragma unroll
    for (int j = 0; j < 4; ++j)
      bv[j] = *(const short8*)&Bs[(wn + j * 16 + rr) * 32 + q * 8];
#pragma unroll
    for (int i = 0; i < 4; ++i)
#pragma unroll
      for (int j = 0; j < 4; ++j)
        acc[i][j] = __builtin_amdgcn_mfma_f32_16x16x32_bf16(av[i], bv[j], acc[i][j], 0, 0, 0);
    __syncthreads();
  }
#pragma unroll
  for (int i = 0; i < 4; ++i)
#pragma unroll
    for (int j = 0; j < 4; ++j)
#pragma unroll
      for (int reg = 0; reg < 4; ++reg) {
        int row = wm + i * 16 + q * 4 + reg;
        int col = wn + j * 16 + rr;
        float vv = acc[i][j][reg] + bias[bn + col];
        Pd[(size_t)(bm + row) * 4096 + bn + col] = f2bf(vv);
      }
}

// ---------------- persistent recurrence kernel (both dirs, all 512 steps) ----------------
// 256 blocks x 256 threads, cooperative. Block: dir = bid&1, m0 = (bid>>1)*8.
// Owns j-rows {g*1024 + m0 + r : g<4, r<8}. W_hh rows live in LDS (bf16) all steps.
// LDS layout (dynamic):
//   ws_lds: bf16[32][1032]  offset 0        (66048 B)   row jl = g*8+r
//   hs_lds: f32 [8][1028]   offset 66048    (32896 B)
//   gates:  f32 [256]       offset 98944    (1024 B)    total 99968 B
__global__ __launch_bounds__(256) void k_rec(const float* __restrict__ Whf,
                                             const float* __restrict__ Whb,
                                             const unsigned short* __restrict__ P,
                                             const int* __restrict__ lengths,
                                             float* __restrict__ h_glob,   // [2][2][8][1024]
                                             float* __restrict__ h_seq) {
  extern __shared__ char smem[];
  unsigned short* w_lds = (unsigned short*)smem;
  float* h_lds = (float*)(smem + 66048);
  float* gates = (float*)(smem + 98944);

  const int bid = blockIdx.x;
  const int dir = bid & 1;
  const int m0 = (bid >> 1) * 8;
  const int tid = threadIdx.x;
  const float* Wh = dir ? Whb : Whf;

  // ---- stage W_hh rows into LDS (once) ----
  for (int i = tid; i < 8192; i += 256) {      // float4 units: 32 rows x 256
    int row = i >> 8, c4 = i & 255;
    int j = (row >> 3) * 1024 + m0 + (row & 7);
    float4 v = *(const float4*)&Wh[(size_t)j * 1024 + c4 * 4];
    ushort4 o;
    o.x = f2bf(v.x); o.y = f2bf(v.y); o.z = f2bf(v.z); o.w = f2bf(v.w);
    *(ushort4*)&w_lds[row * 1032 + c4 * 4] = o;
  }

  const int b = tid & 7;
  const int jl = tid >> 3;                      // 0..31
  const int j = (jl >> 3) * 1024 + m0 + (jl & 7);
  const unsigned short* wrow = w_lds + jl * 1032;
  const float* hrow = h_lds + b * 1028;
  const unsigned short* Pbase = P + (size_t)dir * 16777216 + (size_t)b * 4096 + j;

  // epilogue thread state
  const int b2 = tid & 7, m2 = tid >> 3;        // valid for tid<64
  const int len_e = lengths[b2];
  float c_reg = 0.f;
  const int mg = m0 + m2;

  cooperative_groups::grid_group grid = cooperative_groups::this_grid();

  for (int t = 0; t < 512; ++t) {
    if (t > 0) {
      const float* src = h_glob + (size_t)(t & 1) * 16384 + (size_t)dir * 8192;
      for (int i = tid; i < 2048; i += 256) {   // float4 units
        int bb = i >> 8, c4 = i & 255;
        float4 v = *(const float4*)&src[(size_t)i * 4];
        *(float4*)&h_lds[bb * 1028 + c4 * 4] = v;
      }
    }
    __syncthreads();

    float pv = bfl(Pbase[(size_t)t * 32768]);   // (t*8)*4096
    float acc = 0.f;
    if (t > 0) {
      float2 s01 = {0.f, 0.f}, s23 = {0.f, 0.f};
#pragma unroll 8
      for (int h4 = 0; h4 < 256; ++h4) {
        uint2 wq = *(const uint2*)(wrow + h4 * 4);
        float4 hh = *(const float4*)(hrow + h4 * 4);
        s01.x += __uint_as_float(wq.x << 16) * hh.x;
        s01.y += __uint_as_float(wq.x & 0xffff0000u) * hh.y;
        s23.x += __uint_as_float(wq.y << 16) * hh.z;
        s23.y += __uint_as_float(wq.y & 0xffff0000u) * hh.w;
      }
      acc = (s01.x + s01.y) + (s23.x + s23.y);
    }
    gates[jl * 8 + b] = acc + pv;
    __syncthreads();

    if (tid < 64 && t < len_e) {
      float gi = gates[(0 * 8 + m2) * 8 + b2];
      float gf = gates[(1 * 8 + m2) * 8 + b2];
      float gg = gates[(2 * 8 + m2) * 8 + b2];
      float go = gates[(3 * 8 + m2) * 8 + b2];
      float si = 1.f / (1.f + __expf(-gi));
      float sf = 1.f / (1.f + __expf(-gf));
      float so = 1.f / (1.f + __expf(-go));
      float tg = tanhf(gg);
      float cn = sf * c_reg + si * tg;
      float hn = so * tanhf(cn);
      c_reg = cn;
      h_glob[(size_t)((t + 1) & 1) * 16384 + (size_t)dir * 8192 + (size_t)b2 * 1024 + mg] = hn;
      h_seq[((size_t)(dir * 512 + t) * 8 + b2) * 1024 + mg] = hn;
    }
    grid.sync();
  }
}

// ---------------- emissions: emit[t*8+b][k] = [hf, hb(rev)] @ W_emit^T + b_emit ----------------
__global__ __launch_bounds__(64) void k_emit(const float* __restrict__ h_seq,
    const float* __restrict__ WET, const float* __restrict__ b_emit,
    const int* __restrict__ lengths, float* __restrict__ emit) {
  __shared__ float hl[4][2048];
  const int tid = threadIdx.x;
  const int p0 = blockIdx.x * 4;
  for (int i = 0; i < 32; ++i) {
    int idx = tid + i * 64;          // float4 index 0..2047
    int pl = idx >> 9;
    int r = idx & 511;
    int p = p0 + pl;
    int t = p >> 3, b = p & 7;
    int len = lengths[b];
    float4 v = make_float4(0.f, 0.f, 0.f, 0.f);
    if (t < len) {
      if (r < 256) {
        v = *(const float4*)&h_seq[((size_t)t * 8 + b) * 1024 + r * 4];
      } else {
        int tr = len - 1 - t;
        v = *(const float4*)&h_seq[((size_t)(512 + tr) * 8 + b) * 1024 + (r - 256) * 4];
      }
    }
    *(float4*)&hl[pl][r * 4] = v;
  }
  __syncthreads();
  const int k = tid & 15, pl = tid >> 4;
  const int p = p0 + pl;
  const int t = p >> 3, b = p & 7;
  const int len = lengths[b];
  float acc = 0.f;
  if (t < len) {
    const float* hrow = hl[pl];
#pragma unroll 4
    for (int e4 = 0; e4 < 512; ++e4) {
      float4 h4 = *(const float4*)&hrow[e4 * 4];
      acc += h4.x * WET[(e4 * 4 + 0) * 16 + k]
           + h4.y * WET[(e4 * 4 + 1) * 16 + k]
           + h4.z * WET[(e4 * 4 + 2) * 16 + k]
           + h4.w * WET[(e4 * 4 + 3) * 16 + k];
    }
    acc += b_emit[k];
  }
  emit[(size_t)p * 16 + k] = (t < len) ? acc : 0.f;
}

// ---------------- CRF: gold score + forward algorithm, out[b] = logZ - total ----------------
__global__ __launch_bounds__(128) void k_crf(const float* __restrict__ emit,
    const int* __restrict__ tags, const int* __restrict__ lengths,
    const float* __restrict__ trans, float* __restrict__ out) {
  __shared__ float d_lds[8][17];
  __shared__ float tot[8][17];
  __shared__ float totb[8];
  const int tid = threadIdx.x;
  const int b = tid >> 4, k = tid & 15;
  const int len = lengths[b];

  float part = 0.f;
  for (int t = k; t < 512; t += 16) {
    if (t < len) {
      int tg = tags[b * 512 + t];
      part += emit[((size_t)t * 8 + b) * 16 + tg];
      if (t >= 1) part += trans[tags[b * 512 + t - 1] * 16 + tg];
    }
  }
  tot[b][k] = part;

  float trc[16];
#pragma unroll
  for (int i = 0; i < 16; ++i) trc[i] = trans[i * 16 + k];
  d_lds[b][k] = emit[b * 16 + k];
  __syncthreads();
  if (k == 0) {
    float s = 0.f;
    for (int i = 0; i < 16; ++i) s += tot[b][i];
    totb[b] = s;
  }
  __syncthreads();

  for (int t = 1; t < 512; ++t) {
    float nd = 0.f;
    bool upd = (t < len);
    if (upd) {
      float mx = -3.0e38f;
      float v[16];
#pragma unroll
      for (int i = 0; i < 16; ++i) { v[i] = d_lds[b][i] + trc[i]; mx = fmaxf(mx, v[i]); }
      float s = 0.f;
#pragma unroll
      for (int i = 0; i < 16; ++i) s += __expf(v[i] - mx);
      nd = mx + __logf(s) + emit[((size_t)t * 8 + b) * 16 + k];
    }
    __syncthreads();
    if (upd) d_lds[b][k] = nd;
    __syncthreads();
  }

  if (k == 0) {
    float mx = -3.0e38f;
    for (int i = 0; i < 16; ++i) mx = fmaxf(mx, d_lds[b][i]);
    float s = 0.f;
    for (int i = 0; i < 16; ++i) s += __expf(d_lds[b][i] - mx);
    out[b] = (mx + __logf(s)) - totb[b];
  }
}

extern "C" void kernel_launch(void* const* d_in, const int* in_sizes, int n_in,
                              void* d_out, int out_size, void* d_ws, size_t ws_size,
                              hipStream_t stream) {
  const float* x       = (const float*)d_in[0];
  const int*   tags    = (const int*)d_in[1];
  const int*   lengths = (const int*)d_in[2];
  const float* W_ih_f  = (const float*)d_in[3];
  const float* W_hh_f  = (const float*)d_in[4];
  const float* b_f     = (const float*)d_in[5];
  const float* W_ih_b  = (const float*)d_in[6];
  const float* W_hh_b  = (const float*)d_in[7];
  const float* b_b     = (const float*)d_in[8];
  const float* W_emit  = (const float*)d_in[9];
  const float* b_emit  = (const float*)d_in[10];
  const float* trans   = (const float*)d_in[11];
  float* out = (float*)d_out;
  (void)in_sizes; (void)n_in; (void)out_size; (void)ws_size;

  char* ws = (char*)d_ws;
  unsigned short* A    = (unsigned short*)ws; ws += 16777216;   // 2 x 4096 x 1024 bf16
  unsigned short* Wp   = (unsigned short*)ws; ws += 16777216;   // 2 x 4096 x 1024 bf16
  unsigned short* P    = (unsigned short*)ws; ws += 67108864;   // 2 x 4096 x 4096 bf16
  float* h_seq  = (float*)ws; ws += 33554432;                   // 2 x 512 x 8 x 1024 f32
  float* h_glob = (float*)ws; ws += 131072;                     // 2 x 2 x 8 x 1024 f32
  float* emit   = (float*)ws; ws += 262144;
  float* WET    = (float*)ws; ws += 131072;

  static int attr_done = 0;
  if (!attr_done) {
    hipFuncSetAttribute((const void*)k_rec,
                        hipFuncAttributeMaxDynamicSharedMemorySize, 99968);
    attr_done = 1;
  }

  k_build_A<<<8192, 256, 0, stream>>>(x, lengths, A);
  k_cast_wih<<<8192, 256, 0, stream>>>(W_ih_f, W_ih_b, Wp);
  k_build_wet<<<128, 256, 0, stream>>>(W_emit, WET);
  k_proj<<<dim3(32, 32, 2), 256, 0, stream>>>(A, Wp, b_f, b_b, P);

  {
    const float* whf = W_hh_f; const float* whb = W_hh_b;
    const unsigned short* pp = P; const int* ll = lengths;
    float* hg = h_glob; float* hs = h_seq;
    void* args[] = { &whf, &whb, &pp, &ll, &hg, &hs };
    hipLaunchCooperativeKernel((const void*)k_rec, dim3(256), dim3(256),
                               args, 99968, stream);
  }

  k_emit<<<1024, 64, 0, stream>>>(h_seq, WET, b_emit, lengths, emit);
  k_crf<<<1, 128, 0, stream>>>(emit, tags, lengths, trans, out);
}

// Round 3
// 4832.516 us; speedup vs baseline: 6.8133x; 4.0085x over previous
//
#include <hip/hip_runtime.h>
#include <hip/hip_cooperative_groups.h>
#include <stdint.h>

typedef unsigned int uint;
typedef __attribute__((ext_vector_type(8))) short short8;
typedef __attribute__((ext_vector_type(4))) float f32x4;

#define AS1 __attribute__((address_space(1)))
#define AS3 __attribute__((address_space(3)))

__device__ __forceinline__ unsigned short f2bf(float f) {
  uint u = __float_as_uint(f);
  u += 0x7fffu + ((u >> 16) & 1u);
  return (unsigned short)(u >> 16);
}
__device__ __forceinline__ float bfl(unsigned short s) {
  return __uint_as_float(((uint)s) << 16);
}

// ---------------- build kernels ----------------

// A[dir][m=t*8+b][e] = bf16(x or x_rev), 2 x 4096 x 1024
__global__ __launch_bounds__(256) void k_build_A(const float* __restrict__ x,
                                                 const int* __restrict__ lengths,
                                                 unsigned short* __restrict__ A) {
  int idx = blockIdx.x * 256 + threadIdx.x;   // float4 units, 2*1Mi total
  int dir = idx >> 20;
  int r = idx & 1048575;
  int m = r >> 8;
  int e4 = r & 255;
  int t = m >> 3, b = m & 7;
  int st = t;
  if (dir) { int len = lengths[b]; st = (t < len) ? (len - 1 - t) : t; }
  float4 v = *(const float4*)&x[((size_t)b * 512 + st) * 1024 + e4 * 4];
  ushort4 o;
  o.x = f2bf(v.x); o.y = f2bf(v.y); o.z = f2bf(v.z); o.w = f2bf(v.w);
  *(ushort4*)&A[(size_t)dir * 4194304 + (size_t)m * 1024 + e4 * 4] = o;
}

// Wp[dir][j][e] = bf16(W_ih)
__global__ __launch_bounds__(256) void k_cast_wih(const float* __restrict__ Wf,
                                                  const float* __restrict__ Wb,
                                                  unsigned short* __restrict__ Wp) {
  int idx = blockIdx.x * 256 + threadIdx.x;
  int dir = idx >> 20;
  int r = idx & 1048575;
  const float* src = dir ? Wb : Wf;
  float4 v = *(const float4*)&src[(size_t)r * 4];
  ushort4 o;
  o.x = f2bf(v.x); o.y = f2bf(v.y); o.z = f2bf(v.z); o.w = f2bf(v.w);
  *(ushort4*)&Wp[(size_t)dir * 4194304 + (size_t)r * 4] = o;
}

// WF: W_hh pre-swizzled into MFMA B-fragment order.
// tid -> lane(6) | fi(6) | w(2) | mc(5) | dir(1); fi = kt*2+nt
// frag element: B[n = nt*16 + (lane&15)][k = kt*32 + (lane>>4)*8 + 0..7]
// j = (n_local>>5)*1024 + mc*32 + (n_local&31), n_local = w*32+nt*16+(lane&15)
__global__ __launch_bounds__(256) void k_build_wf(const float* __restrict__ Wf,
                                                  const float* __restrict__ Wb,
                                                  unsigned short* __restrict__ WF,
                                                  uint* __restrict__ cnt) {
  int tid = blockIdx.x * 256 + threadIdx.x;   // 1Mi
  if (tid == 0) { cnt[0] = 0u; cnt[1] = 0u; }
  int lane = tid & 63;
  int fi = (tid >> 6) & 63;
  int w = (tid >> 12) & 3;
  int mc = (tid >> 14) & 31;
  int dir = (tid >> 19) & 1;
  int kt = fi >> 1, nt = fi & 1;
  int n_local = w * 32 + nt * 16 + (lane & 15);
  int j = (n_local >> 5) * 1024 + mc * 32 + (n_local & 31);
  int k0 = kt * 32 + (lane >> 4) * 8;
  const float* src = dir ? Wb : Wf;
  const float* s = &src[(size_t)j * 1024 + k0];
  float4 v0 = *(const float4*)s;
  float4 v1 = *(const float4*)(s + 4);
  ushort4 oa, ob;
  oa.x = f2bf(v0.x); oa.y = f2bf(v0.y); oa.z = f2bf(v0.z); oa.w = f2bf(v0.w);
  ob.x = f2bf(v1.x); ob.y = f2bf(v1.y); ob.z = f2bf(v1.z); ob.w = f2bf(v1.w);
  *(ushort4*)&WF[(size_t)tid * 8] = oa;
  *(ushort4*)&WF[(size_t)tid * 8 + 4] = ob;
}

// WET[e][k] = W_emit[k][e]  (fp32)
__global__ __launch_bounds__(256) void k_build_wet(const float* __restrict__ We,
                                                   float* __restrict__ WET) {
  int idx = blockIdx.x * 256 + threadIdx.x;  // 32768
  int e = idx >> 4, k = idx & 15;
  WET[(size_t)e * 16 + k] = We[(size_t)k * 2048 + e];
}

// ---------------- projection GEMM (bf16 MFMA): P[dir][m][j] = A @ W_ih^T + b ----------------
__global__ __launch_bounds__(256) void k_proj(const unsigned short* __restrict__ A,
                                              const unsigned short* __restrict__ Wp,
                                              const float* __restrict__ bfv,
                                              const float* __restrict__ bbv,
                                              unsigned short* __restrict__ P) {
  const int dir = blockIdx.z;
  const unsigned short* Ad = A + (size_t)dir * 4194304;
  const unsigned short* Wd = Wp + (size_t)dir * 4194304;
  const float* bias = dir ? bbv : bfv;
  unsigned short* Pd = P + (size_t)dir * 16777216;
  const int bm = blockIdx.x * 128;
  const int bn = blockIdx.y * 128;
  __shared__ unsigned short As[128 * 32];
  __shared__ unsigned short Bs[128 * 32];
  const int tid = threadIdx.x;
  const int w = tid >> 6, lane = tid & 63;
  const int wm = (w >> 1) * 64, wn = (w & 1) * 64;
  const int q = lane >> 4, rr = lane & 15;

  f32x4 acc[4][4];
#pragma unroll
  for (int i = 0; i < 4; ++i)
#pragma unroll
    for (int j = 0; j < 4; ++j) acc[i][j] = (f32x4){0.f, 0.f, 0.f, 0.f};

  for (int k0 = 0; k0 < 1024; k0 += 32) {
#pragma unroll
    for (int i = 0; i < 2; ++i) {
      int c = i * 256 + tid;
      int row = c >> 2, col = (c & 3) * 8;
      const unsigned short* ga = Ad + (size_t)(bm + row) * 1024 + k0 + col;
      const unsigned short* gb = Wd + (size_t)(bn + row) * 1024 + k0 + col;
      __builtin_amdgcn_global_load_lds((const AS1 void*)ga,
                                       (AS3 void*)&As[(i * 256 + w * 64) * 8], 16, 0, 0);
      __builtin_amdgcn_global_load_lds((const AS1 void*)gb,
                                       (AS3 void*)&Bs[(i * 256 + w * 64) * 8], 16, 0, 0);
    }
    __syncthreads();
    short8 av[4], bv[4];
#pragma unroll
    for (int i = 0; i < 4; ++i)
      av[i] = *(const short8*)&As[(wm + i * 16 + rr) * 32 + q * 8];
#pragma unroll
    for (int j = 0; j < 4; ++j)
      bv[j] = *(const short8*)&Bs[(wn + j * 16 + rr) * 32 + q * 8];
#pragma unroll
    for (int i = 0; i < 4; ++i)
#pragma unroll
      for (int j = 0; j < 4; ++j)
        acc[i][j] = __builtin_amdgcn_mfma_f32_16x16x32_bf16(av[i], bv[j], acc[i][j], 0, 0, 0);
    __syncthreads();
  }
#pragma unroll
  for (int i = 0; i < 4; ++i)
#pragma unroll
    for (int j = 0; j < 4; ++j)
#pragma unroll
      for (int reg = 0; reg < 4; ++reg) {
        int row = wm + i * 16 + q * 4 + reg;
        int col = wn + j * 16 + rr;
        float vv = acc[i][j][reg] + bias[bn + col];
        Pd[(size_t)(bm + row) * 4096 + bn + col] = f2bf(vv);
      }
}

// ---------------- persistent recurrence: 64 blocks, MFMA batch-merged, chain barriers ----
// block: dir = bid&1, mc = bid>>1 (m-range mc*32..+31). 256 threads = 4 waves.
// Wave w owns j-rows n_local in [w*32, w*32+32) -> gate g = w, since n_local>>5 == w.
// Per step: D[8 batches][128 rows] = h[8][1024] x W^T via mfma_f32_16x16x32_bf16,
// M=8 valid rows (rows 8-15 garbage, ignored). B-frags preswizzled in WF (L2-resident).
// h exchange: packed bf16x2 agent-scope relaxed atomics; per-dir 32-block barrier via
// monotonic counter; ping-pong h buffers (WAR separated by one full round).
__global__ __launch_bounds__(256) void k_rec(const unsigned short* __restrict__ WF,
                                             const unsigned short* __restrict__ P,
                                             const int* __restrict__ lengths,
                                             uint* __restrict__ hg,    // [2buf][2dir][8b][512] u32
                                             uint* __restrict__ cnt,   // [2]
                                             float* __restrict__ h_seq) {
  __shared__ unsigned short h_lds[8 * 1032];   // rows stride 2064B (16B-aligned, spreads banks)
  __shared__ float gl[128 * 9];
  __shared__ float htmp[256];

  const int bid = blockIdx.x;
  const int dir = bid & 1;
  const int mc = bid >> 1;
  const int tid = threadIdx.x;
  const int w = tid >> 6, lane = tid & 63;
  const int q = lane >> 4, hb = lane & 7;

  // epilogue identity: thread -> (b, mm)
  const int eb = tid >> 5, mm = tid & 31;
  const int len_e = lengths[eb];
  float c_reg = 0.f, h_reg = 0.f;

  const unsigned short* Pd = P + (size_t)dir * 16777216 + (size_t)(1024 * 0) + mc * 32 + mm;
  const unsigned short* wfw = WF + ((size_t)((dir * 32 + mc) * 4 + w) * 64) * 512;
  uint* cptr = &cnt[dir];

  for (int t = 0; t < 512; ++t) {
    // ---- P prefetch (h-independent): 4 gate biases for (eb, mm) ----
    const unsigned short* prow = Pd + (size_t)(t * 8 + eb) * 4096;
    unsigned short p0 = prow[0];
    unsigned short p1 = prow[1024];
    unsigned short p2 = prow[2048];
    unsigned short p3 = prow[3072];

    f32x4 acc0 = (f32x4){0.f, 0.f, 0.f, 0.f};
    f32x4 acc1 = (f32x4){0.f, 0.f, 0.f, 0.f};

    if (t > 0) {
      // ---- wait for all same-dir blocks to have published h[t-1] ----
      if (tid < 64) {
        while (__hip_atomic_load(cptr, __ATOMIC_RELAXED, __HIP_MEMORY_SCOPE_AGENT)
               < (uint)(32 * t)) {
          __builtin_amdgcn_s_sleep(1);
        }
      }
      __syncthreads();
      // ---- stage h[t-1] (bf16-packed) into LDS ----
      const uint* src = hg + (size_t)(((t - 1) & 1) * 2 + dir) * 4096;
      for (int r = 0; r < 16; ++r) {
        int i = tid + r * 256;             // 4096 u32
        uint v = __hip_atomic_load(&src[i], __ATOMIC_RELAXED, __HIP_MEMORY_SCOPE_AGENT);
        int b = i >> 9, ku = i & 511;
        *(uint*)&h_lds[b * 1032 + ku * 2] = v;
      }
      __syncthreads();
      // ---- K-loop: 32 k-tiles ----
#pragma unroll 8
      for (int kt = 0; kt < 32; ++kt) {
        short8 a = *(const short8*)&h_lds[hb * 1032 + kt * 32 + q * 8];
        short8 b0 = *(const short8*)&wfw[(size_t)(kt * 2 + 0) * 512 + lane * 8];
        short8 b1 = *(const short8*)&wfw[(size_t)(kt * 2 + 1) * 512 + lane * 8];
        acc0 = __builtin_amdgcn_mfma_f32_16x16x32_bf16(a, b0, acc0, 0, 0, 0);
        acc1 = __builtin_amdgcn_mfma_f32_16x16x32_bf16(a, b1, acc1, 0, 0, 0);
      }
    }

    // ---- D -> gates LDS (valid rows 0..7 live in lanes 0..31) ----
    if (lane < 32) {
#pragma unroll
      for (int reg = 0; reg < 4; ++reg) {
        int b = q * 4 + reg;
        gl[(w * 32 + (lane & 15)) * 9 + b] = acc0[reg];
        gl[(w * 32 + 16 + (lane & 15)) * 9 + b] = acc1[reg];
      }
    }
    __syncthreads();

    // ---- epilogue: activations for (eb, mm) ----
    if (t < len_e) {
      float gi = gl[(0 * 32 + mm) * 9 + eb] + bfl(p0);
      float gf = gl[(1 * 32 + mm) * 9 + eb] + bfl(p1);
      float gg = gl[(2 * 32 + mm) * 9 + eb] + bfl(p2);
      float go = gl[(3 * 32 + mm) * 9 + eb] + bfl(p3);
      float si = 1.f / (1.f + __expf(-gi));
      float sf = 1.f / (1.f + __expf(-gf));
      float so = 1.f / (1.f + __expf(-go));
      float tg = tanhf(gg);
      float cn = sf * c_reg + si * tg;
      float hn = so * tanhf(cn);
      c_reg = cn;
      h_reg = hn;
      h_seq[((size_t)(dir * 512 + t) * 8 + eb) * 1024 + mc * 32 + mm] = hn;
    }
    htmp[eb * 32 + mm] = h_reg;   // frozen batches keep republishing last h
    __syncthreads();

    // ---- publish h[t] chunk: pack bf16x2, agent atomic stores ----
    if (tid < 128) {
      int b = tid >> 4, p = tid & 15;
      uint pk = (uint)f2bf(htmp[b * 32 + 2 * p]) |
                ((uint)f2bf(htmp[b * 32 + 2 * p + 1]) << 16);
      uint* dst = hg + (size_t)((t & 1) * 2 + dir) * 4096 + (size_t)b * 512 + mc * 16 + p;
      __hip_atomic_store(dst, pk, __ATOMIC_RELAXED, __HIP_MEMORY_SCOPE_AGENT);
    }
    __builtin_amdgcn_s_waitcnt(0);    // per-wave: stores acked at coherence point
    __syncthreads();                  // all waves drained
    if (tid == 0 && t < 511)
      __hip_atomic_fetch_add(cptr, 1u, __ATOMIC_RELAXED, __HIP_MEMORY_SCOPE_AGENT);
  }
}

// ---------------- emissions: emit[t*8+b][k] = [hf, hb(rev)] @ W_emit^T + b_emit ----------------
__global__ __launch_bounds__(64) void k_emit(const float* __restrict__ h_seq,
    const float* __restrict__ WET, const float* __restrict__ b_emit,
    const int* __restrict__ lengths, float* __restrict__ emit) {
  __shared__ float hl[4][2048];
  const int tid = threadIdx.x;
  const int p0 = blockIdx.x * 4;
  for (int i = 0; i < 32; ++i) {
    int idx = tid + i * 64;          // float4 index 0..2047
    int pl = idx >> 9;
    int r = idx & 511;
    int p = p0 + pl;
    int t = p >> 3, b = p & 7;
    int len = lengths[b];
    float4 v = make_float4(0.f, 0.f, 0.f, 0.f);
    if (t < len) {
      if (r < 256) {
        v = *(const float4*)&h_seq[((size_t)t * 8 + b) * 1024 + r * 4];
      } else {
        int tr = len - 1 - t;
        v = *(const float4*)&h_seq[((size_t)(512 + tr) * 8 + b) * 1024 + (r - 256) * 4];
      }
    }
    *(float4*)&hl[pl][r * 4] = v;
  }
  __syncthreads();
  const int k = tid & 15, pl = tid >> 4;
  const int p = p0 + pl;
  const int t = p >> 3, b = p & 7;
  const int len = lengths[b];
  float acc = 0.f;
  if (t < len) {
    const float* hrow = hl[pl];
#pragma unroll 4
    for (int e4 = 0; e4 < 512; ++e4) {
      float4 h4 = *(const float4*)&hrow[e4 * 4];
      acc += h4.x * WET[(e4 * 4 + 0) * 16 + k]
           + h4.y * WET[(e4 * 4 + 1) * 16 + k]
           + h4.z * WET[(e4 * 4 + 2) * 16 + k]
           + h4.w * WET[(e4 * 4 + 3) * 16 + k];
    }
    acc += b_emit[k];
  }
  emit[(size_t)p * 16 + k] = (t < len) ? acc : 0.f;
}

// ---------------- CRF: gold score + forward algorithm, out[b] = logZ - total ----------------
__global__ __launch_bounds__(128) void k_crf(const float* __restrict__ emit,
    const int* __restrict__ tags, const int* __restrict__ lengths,
    const float* __restrict__ trans, float* __restrict__ out) {
  __shared__ float d_lds[8][17];
  __shared__ float tot[8][17];
  __shared__ float totb[8];
  const int tid = threadIdx.x;
  const int b = tid >> 4, k = tid & 15;
  const int len = lengths[b];

  float part = 0.f;
  for (int t = k; t < 512; t += 16) {
    if (t < len) {
      int tg = tags[b * 512 + t];
      part += emit[((size_t)t * 8 + b) * 16 + tg];
      if (t >= 1) part += trans[tags[b * 512 + t - 1] * 16 + tg];
    }
  }
  tot[b][k] = part;

  float trc[16];
#pragma unroll
  for (int i = 0; i < 16; ++i) trc[i] = trans[i * 16 + k];
  d_lds[b][k] = emit[b * 16 + k];
  __syncthreads();
  if (k == 0) {
    float s = 0.f;
    for (int i = 0; i < 16; ++i) s += tot[b][i];
    totb[b] = s;
  }
  __syncthreads();

  for (int t = 1; t < 512; ++t) {
    float nd = 0.f;
    bool upd = (t < len);
    if (upd) {
      float mx = -3.0e38f;
      float v[16];
#pragma unroll
      for (int i = 0; i < 16; ++i) { v[i] = d_lds[b][i] + trc[i]; mx = fmaxf(mx, v[i]); }
      float s = 0.f;
#pragma unroll
      for (int i = 0; i < 16; ++i) s += __expf(v[i] - mx);
      nd = mx + __logf(s) + emit[((size_t)t * 8 + b) * 16 + k];
    }
    __syncthreads();
    if (upd) d_lds[b][k] = nd;
    __syncthreads();
  }

  if (k == 0) {
    float mx = -3.0e38f;
    for (int i = 0; i < 16; ++i) mx = fmaxf(mx, d_lds[b][i]);
    float s = 0.f;
    for (int i = 0; i < 16; ++i) s += __expf(d_lds[b][i] - mx);
    out[b] = (mx + __logf(s)) - totb[b];
  }
}

extern "C" void kernel_launch(void* const* d_in, const int* in_sizes, int n_in,
                              void* d_out, int out_size, void* d_ws, size_t ws_size,
                              hipStream_t stream) {
  const float* x       = (const float*)d_in[0];
  const int*   tags    = (const int*)d_in[1];
  const int*   lengths = (const int*)d_in[2];
  const float* W_ih_f  = (const float*)d_in[3];
  const float* W_hh_f  = (const float*)d_in[4];
  const float* b_f     = (const float*)d_in[5];
  const float* W_ih_b  = (const float*)d_in[6];
  const float* W_hh_b  = (const float*)d_in[7];
  const float* b_b     = (const float*)d_in[8];
  const float* W_emit  = (const float*)d_in[9];
  const float* b_emit  = (const float*)d_in[10];
  const float* trans   = (const float*)d_in[11];
  float* out = (float*)d_out;
  (void)in_sizes; (void)n_in; (void)out_size; (void)ws_size;

  char* ws = (char*)d_ws;
  unsigned short* A    = (unsigned short*)ws; ws += 16777216;   // 2 x 4096 x 1024 bf16
  unsigned short* Wp   = (unsigned short*)ws; ws += 16777216;   // 2 x 4096 x 1024 bf16
  unsigned short* WF   = (unsigned short*)ws; ws += 16777216;   // MFMA-frag-ordered W_hh
  unsigned short* P    = (unsigned short*)ws; ws += 67108864;   // 2 x 4096 x 4096 bf16
  float* h_seq = (float*)ws; ws += 33554432;                    // 2 x 512 x 8 x 1024 f32
  uint* hg     = (uint*)ws;  ws += 65536;                       // 2buf x 2dir x 8 x 512 u32
  uint* cnt    = (uint*)ws;  ws += 4096;
  float* emit  = (float*)ws; ws += 262144;
  float* WET   = (float*)ws; ws += 131072;

  k_build_A<<<8192, 256, 0, stream>>>(x, lengths, A);
  k_cast_wih<<<8192, 256, 0, stream>>>(W_ih_f, W_ih_b, Wp);
  k_build_wf<<<4096, 256, 0, stream>>>(W_hh_f, W_hh_b, WF, cnt);
  k_build_wet<<<128, 256, 0, stream>>>(W_emit, WET);
  k_proj<<<dim3(32, 32, 2), 256, 0, stream>>>(A, Wp, b_f, b_b, P);

  {
    const unsigned short* wf = WF;
    const unsigned short* pp = P;
    const int* ll = lengths;
    uint* hgp = hg; uint* cp = cnt; float* hs = h_seq;
    void* args[] = { &wf, &pp, &ll, &hgp, &cp, &hs };
    hipLaunchCooperativeKernel((const void*)k_rec, dim3(64), dim3(256),
                               args, 0, stream);
  }

  k_emit<<<1024, 64, 0, stream>>>(h_seq, WET, b_emit, lengths, emit);
  k_crf<<<1, 128, 0, stream>>>(emit, tags, lengths, trans, out);
}

// Round 5
// 3090.538 us; speedup vs baseline: 10.6535x; 1.5636x over previous
//
#include <hip/hip_runtime.h>
#include <hip/hip_cooperative_groups.h>
#include <stdint.h>

typedef unsigned int uint;
typedef unsigned long long ull;
typedef __attribute__((ext_vector_type(8))) short short8;
typedef __attribute__((ext_vector_type(4))) float f32x4;

#define AS1 __attribute__((address_space(1)))
#define AS3 __attribute__((address_space(3)))

__device__ __forceinline__ unsigned short f2bf(float f) {
  uint u = __float_as_uint(f);
  u += 0x7fffu + ((u >> 16) & 1u);
  return (unsigned short)(u >> 16);
}
__device__ __forceinline__ float bfl(unsigned short s) {
  return __uint_as_float(((uint)s) << 16);
}

// ---------------- build kernels ----------------

// A[dir][m=t*8+b][e] = bf16(x or x_rev), 2 x 4096 x 1024
__global__ __launch_bounds__(256) void k_build_A(const float* __restrict__ x,
                                                 const int* __restrict__ lengths,
                                                 unsigned short* __restrict__ A) {
  int idx = blockIdx.x * 256 + threadIdx.x;   // float4 units, 2*1Mi total
  int dir = idx >> 20;
  int r = idx & 1048575;
  int m = r >> 8;
  int e4 = r & 255;
  int t = m >> 3, b = m & 7;
  int st = t;
  if (dir) { int len = lengths[b]; st = (t < len) ? (len - 1 - t) : t; }
  float4 v = *(const float4*)&x[((size_t)b * 512 + st) * 1024 + e4 * 4];
  ushort4 o;
  o.x = f2bf(v.x); o.y = f2bf(v.y); o.z = f2bf(v.z); o.w = f2bf(v.w);
  *(ushort4*)&A[(size_t)dir * 4194304 + (size_t)m * 1024 + e4 * 4] = o;
}

// Wp[dir][j][e] = bf16(W_ih)
__global__ __launch_bounds__(256) void k_cast_wih(const float* __restrict__ Wf,
                                                  const float* __restrict__ Wb,
                                                  unsigned short* __restrict__ Wp) {
  int idx = blockIdx.x * 256 + threadIdx.x;
  int dir = idx >> 20;
  int r = idx & 1048575;
  const float* src = dir ? Wb : Wf;
  float4 v = *(const float4*)&src[(size_t)r * 4];
  ushort4 o;
  o.x = f2bf(v.x); o.y = f2bf(v.y); o.z = f2bf(v.z); o.w = f2bf(v.w);
  *(ushort4*)&Wp[(size_t)dir * 4194304 + (size_t)r * 4] = o;
}

// WF: W_hh in MFMA B-fragment order, per (dir, mc) slice of 32 j-rows.
// gtid = lane(6) | f(6) | mc(7) | dir(1); f = kt*2+nt
// B[n_local = nt*16+(lane&15)][k = kt*32+(lane>>4)*8 + v], v<8
// j = (n_local>>3)*1024 + mc*8 + (n_local&7)
__global__ __launch_bounds__(256) void k_build_wf(const float* __restrict__ Wf,
                                                  const float* __restrict__ Wb,
                                                  unsigned short* __restrict__ WF) {
  int gtid = blockIdx.x * 256 + threadIdx.x;   // 2^20
  int lane = gtid & 63;
  int f    = (gtid >> 6) & 63;
  int mc   = (gtid >> 12) & 127;
  int dir  = (gtid >> 19) & 1;
  int kt = f >> 1, nt = f & 1;
  int n_local = nt * 16 + (lane & 15);
  int j = (n_local >> 3) * 1024 + mc * 8 + (n_local & 7);
  int k0 = kt * 32 + (lane >> 4) * 8;
  const float* src = dir ? Wb : Wf;
  const float* s = &src[(size_t)j * 1024 + k0];
  float4 v0 = *(const float4*)s;
  float4 v1 = *(const float4*)(s + 4);
  ushort4 oa, ob;
  oa.x = f2bf(v0.x); oa.y = f2bf(v0.y); oa.z = f2bf(v0.z); oa.w = f2bf(v0.w);
  ob.x = f2bf(v1.x); ob.y = f2bf(v1.y); ob.z = f2bf(v1.z); ob.w = f2bf(v1.w);
  *(ushort4*)&WF[(size_t)gtid * 8] = oa;
  *(ushort4*)&WF[(size_t)gtid * 8 + 4] = ob;
}

// WET[e][k] = W_emit[k][e]  (fp32)
__global__ __launch_bounds__(256) void k_build_wet(const float* __restrict__ We,
                                                   float* __restrict__ WET) {
  int idx = blockIdx.x * 256 + threadIdx.x;  // 32768
  int e = idx >> 4, k = idx & 15;
  WET[(size_t)e * 16 + k] = We[(size_t)k * 2048 + e];
}

// ---------------- projection GEMM (bf16 MFMA): P[dir][m][j] = A @ W_ih^T + b ----------------
__global__ __launch_bounds__(256) void k_proj(const unsigned short* __restrict__ A,
                                              const unsigned short* __restrict__ Wp,
                                              const float* __restrict__ bfv,
                                              const float* __restrict__ bbv,
                                              unsigned short* __restrict__ P) {
  const int dir = blockIdx.z;
  const unsigned short* Ad = A + (size_t)dir * 4194304;
  const unsigned short* Wd = Wp + (size_t)dir * 4194304;
  const float* bias = dir ? bbv : bfv;
  unsigned short* Pd = P + (size_t)dir * 16777216;
  const int bm = blockIdx.x * 128;
  const int bn = blockIdx.y * 128;
  __shared__ unsigned short As[128 * 32];
  __shared__ unsigned short Bs[128 * 32];
  const int tid = threadIdx.x;
  const int w = tid >> 6, lane = tid & 63;
  const int wm = (w >> 1) * 64, wn = (w & 1) * 64;
  const int q = lane >> 4, rr = lane & 15;

  f32x4 acc[4][4];
#pragma unroll
  for (int i = 0; i < 4; ++i)
#pragma unroll
    for (int j = 0; j < 4; ++j) acc[i][j] = (f32x4){0.f, 0.f, 0.f, 0.f};

  for (int k0 = 0; k0 < 1024; k0 += 32) {
#pragma unroll
    for (int i = 0; i < 2; ++i) {
      int c = i * 256 + tid;
      int row = c >> 2, col = (c & 3) * 8;
      const unsigned short* ga = Ad + (size_t)(bm + row) * 1024 + k0 + col;
      const unsigned short* gb = Wd + (size_t)(bn + row) * 1024 + k0 + col;
      __builtin_amdgcn_global_load_lds((const AS1 void*)ga,
                                       (AS3 void*)&As[(i * 256 + w * 64) * 8], 16, 0, 0);
      __builtin_amdgcn_global_load_lds((const AS1 void*)gb,
                                       (AS3 void*)&Bs[(i * 256 + w * 64) * 8], 16, 0, 0);
    }
    __syncthreads();
    short8 av[4], bv[4];
#pragma unroll
    for (int i = 0; i < 4; ++i)
      av[i] = *(const short8*)&As[(wm + i * 16 + rr) * 32 + q * 8];
#pragma unroll
    for (int j = 0; j < 4; ++j)
      bv[j] = *(const short8*)&Bs[(wn + j * 16 + rr) * 32 + q * 8];
#pragma unroll
    for (int i = 0; i < 4; ++i)
#pragma unroll
      for (int j = 0; j < 4; ++j)
        acc[i][j] = __builtin_amdgcn_mfma_f32_16x16x32_bf16(av[i], bv[j], acc[i][j], 0, 0, 0);
    __syncthreads();
  }
#pragma unroll
  for (int i = 0; i < 4; ++i)
#pragma unroll
    for (int j = 0; j < 4; ++j)
#pragma unroll
      for (int reg = 0; reg < 4; ++reg) {
        int row = wm + i * 16 + q * 4 + reg;
        int col = wn + j * 16 + rr;
        float vv = acc[i][j][reg] + bias[bn + col];
        Pd[(size_t)(bm + row) * 4096 + bn + col] = f2bf(vv);
      }
}

// ---------------- persistent recurrence: 256 blocks, W_hh resident in LDS ----------------
// block: dir = bid&1, mc = bid>>1 (mc<128). Owns j-rows {g*1024 + mc*8 + r : g<4, r<8}.
// Per step: D[8 batches][32 j-rows] = h[8][1024] x W^T, 2 n-tiles on waves 1,2.
// h exchange: 128B/block chunks, 2xu64 agent atomics; per-block monotonic flags.
// LDS: w_lds 65536B | h_lds 16x1056 shorts 33792B | gl 32x9 f32 1152B | htmp 64 f32 256B
__global__ __launch_bounds__(256) void k_rec(const unsigned short* __restrict__ WF,
                                             const unsigned short* __restrict__ P,
                                             const int* __restrict__ lengths,
                                             uint* __restrict__ hg,     // [2buf][2dir][8][512] u32
                                             uint* __restrict__ flags,  // [2dir][128]
                                             float* __restrict__ h_seq) {
  extern __shared__ char smem[];
  unsigned short* w_lds = (unsigned short*)smem;             // 32768 shorts = 65536 B
  unsigned short* h_lds = (unsigned short*)(smem + 65536);   // 16 x 1056 shorts
  float* gl   = (float*)(smem + 99328);                      // 32 x 9
  float* htmp = (float*)(smem + 100480);                     // 64

  const int bid = blockIdx.x;
  const int dir = bid & 1;
  const int mc  = bid >> 1;
  const int tid = threadIdx.x;
  const int w   = tid >> 6, lane = tid & 63;
  const int q   = lane >> 4;
  const int nt  = w - 1;                 // waves 1,2 -> n-tiles 0,1

  // ---- stage W slice into LDS (once): 32768 shorts = 4096 uint4 ----
  {
    const uint4* src = (const uint4*)(WF + (size_t)(dir * 128 + mc) * 32768);
    uint4* dst = (uint4*)w_lds;
#pragma unroll
    for (int r_ = 0; r_ < 16; ++r_) dst[tid + 256 * r_] = src[tid + 256 * r_];
  }

  // epilogue identity (tid<64): b = tid>>3, r = tid&7
  const int eb = tid >> 3, er = tid & 7;
  const int len_e = (tid < 64) ? lengths[eb] : 0;
  float c_reg = 0.f, h_reg = 0.f;
  uint* flg = flags + dir * 128;
  __syncthreads();

  for (int t = 0; t < 512; ++t) {
    // ---- P prefetch (raw ushorts; converted only in epilogue) ----
    unsigned short pv0 = 0, pv1 = 0, pv2 = 0, pv3 = 0;
    if (tid < 64) {
      const unsigned short* prow =
          P + (size_t)dir * 16777216 + (size_t)(t * 8 + eb) * 4096 + mc * 8 + er;
      pv0 = prow[0]; pv1 = prow[1024]; pv2 = prow[2048]; pv3 = prow[3072];
    }

    if (t > 0) {
      // ---- wait: all same-dir blocks published h[t-1] (flag >= t) ----
      if (tid < 64) {
        uint need = (uint)t;
        for (;;) {
          uint a = __hip_atomic_load(&flg[tid], __ATOMIC_RELAXED, __HIP_MEMORY_SCOPE_AGENT);
          uint b2 = __hip_atomic_load(&flg[64 + tid], __ATOMIC_RELAXED, __HIP_MEMORY_SCOPE_AGENT);
          if (__ballot((a < need) || (b2 < need)) == 0ull) break;
        }
      }
      __syncthreads();                                   // B1
      // ---- stage h[t-1] into LDS (bf16) ----
      const ull* hsrc = (const ull*)(hg + (size_t)(((t - 1) & 1) * 2 + dir) * 4096);
#pragma unroll
      for (int r_ = 0; r_ < 8; ++r_) {
        int u = tid + 256 * r_;                          // u64 index, 2048 total
        ull v = __hip_atomic_load(&hsrc[u], __ATOMIC_RELAXED, __HIP_MEMORY_SCOPE_AGENT);
        int b_ = u >> 8, c_ = u & 255;
        *(ull*)&h_lds[b_ * 1056 + c_ * 4] = v;
      }
      __syncthreads();                                   // B2
      // ---- MFMA: waves 1,2 ----
      if (nt == 0 || nt == 1) {
        f32x4 a4 = (f32x4){0.f, 0.f, 0.f, 0.f};
#pragma unroll 8
        for (int kt = 0; kt < 32; ++kt) {
          short8 av = *(const short8*)&h_lds[(lane & 7) * 1056 + kt * 32 + q * 8];
          short8 bv = *(const short8*)&w_lds[(kt * 2 + nt) * 512 + lane * 8];
          a4 = __builtin_amdgcn_mfma_f32_16x16x32_bf16(av, bv, a4, 0, 0, 0);
        }
        if (q < 2) {
#pragma unroll
          for (int reg = 0; reg < 4; ++reg)
            gl[(nt * 16 + (lane & 15)) * 9 + q * 4 + reg] = a4[reg];
        }
      }
    }
    __syncthreads();                                     // B3 (gl ready)

    // ---- epilogue: wave 0, one (b, m) pair per thread ----
    if (tid < 64 && t < len_e) {
      float g0 = (t > 0) ? gl[(0 * 8 + er) * 9 + eb] : 0.f;
      float g1 = (t > 0) ? gl[(1 * 8 + er) * 9 + eb] : 0.f;
      float g2 = (t > 0) ? gl[(2 * 8 + er) * 9 + eb] : 0.f;
      float g3 = (t > 0) ? gl[(3 * 8 + er) * 9 + eb] : 0.f;
      float gi = g0 + bfl(pv0);
      float gf = g1 + bfl(pv1);
      float gg = g2 + bfl(pv2);
      float go = g3 + bfl(pv3);
      float si = 1.f / (1.f + __expf(-gi));
      float sf = 1.f / (1.f + __expf(-gf));
      float so = 1.f / (1.f + __expf(-go));
      float tg = tanhf(gg);
      float cn = sf * c_reg + si * tg;
      float hn = so * tanhf(cn);
      c_reg = cn;
      h_reg = hn;
      h_seq[((size_t)(dir * 512 + t) * 8 + eb) * 1024 + mc * 8 + er] = hn;
    }
    if (tid < 64) htmp[tid] = h_reg;      // wave-local LDS, in-order within wave 0
    if (tid < 8) {
      float4 ha = *(const float4*)&htmp[tid * 8];
      float4 hb2 = *(const float4*)&htmp[tid * 8 + 4];
      uint u0 = (uint)f2bf(ha.x) | ((uint)f2bf(ha.y) << 16);
      uint u1 = (uint)f2bf(ha.z) | ((uint)f2bf(ha.w) << 16);
      uint u2 = (uint)f2bf(hb2.x) | ((uint)f2bf(hb2.y) << 16);
      uint u3 = (uint)f2bf(hb2.z) | ((uint)f2bf(hb2.w) << 16);
      ull q0 = (ull)u0 | ((ull)u1 << 32);
      ull q1 = (ull)u2 | ((ull)u3 << 32);
      ull* dst = (ull*)(hg + (size_t)((t & 1) * 2 + dir) * 4096) + (size_t)tid * 256 + mc * 2;
      __hip_atomic_store(&dst[0], q0, __ATOMIC_RELAXED, __HIP_MEMORY_SCOPE_AGENT);
      __hip_atomic_store(&dst[1], q1, __ATOMIC_RELAXED, __HIP_MEMORY_SCOPE_AGENT);
    }
    if (tid < 64) {
      __builtin_amdgcn_s_waitcnt(0);      // wave 0: h stores acked at coherence point
      if (tid == 0)
        __hip_atomic_store(&flg[mc], (uint)(t + 1), __ATOMIC_RELAXED, __HIP_MEMORY_SCOPE_AGENT);
    }
  }
}

// ---------------- emissions: emit[t*8+b][k] = [hf, hb(rev)] @ W_emit^T + b_emit ----------------
__global__ __launch_bounds__(64) void k_emit(const float* __restrict__ h_seq,
    const float* __restrict__ WET, const float* __restrict__ b_emit,
    const int* __restrict__ lengths, float* __restrict__ emit) {
  __shared__ float hl[4][2048];
  const int tid = threadIdx.x;
  const int p0 = blockIdx.x * 4;
  for (int i = 0; i < 32; ++i) {
    int idx = tid + i * 64;          // float4 index 0..2047
    int pl = idx >> 9;
    int r = idx & 511;
    int p = p0 + pl;
    int t = p >> 3, b = p & 7;
    int len = lengths[b];
    float4 v = make_float4(0.f, 0.f, 0.f, 0.f);
    if (t < len) {
      if (r < 256) {
        v = *(const float4*)&h_seq[((size_t)t * 8 + b) * 1024 + r * 4];
      } else {
        int tr = len - 1 - t;
        v = *(const float4*)&h_seq[((size_t)(512 + tr) * 8 + b) * 1024 + (r - 256) * 4];
      }
    }
    *(float4*)&hl[pl][r * 4] = v;
  }
  __syncthreads();
  const int k = tid & 15, pl = tid >> 4;
  const int p = p0 + pl;
  const int t = p >> 3, b = p & 7;
  const int len = lengths[b];
  float acc = 0.f;
  if (t < len) {
    const float* hrow = hl[pl];
#pragma unroll 4
    for (int e4 = 0; e4 < 512; ++e4) {
      float4 h4 = *(const float4*)&hrow[e4 * 4];
      acc += h4.x * WET[(e4 * 4 + 0) * 16 + k]
           + h4.y * WET[(e4 * 4 + 1) * 16 + k]
           + h4.z * WET[(e4 * 4 + 2) * 16 + k]
           + h4.w * WET[(e4 * 4 + 3) * 16 + k];
    }
    acc += b_emit[k];
  }
  emit[(size_t)p * 16 + k] = (t < len) ? acc : 0.f;
}

// ---------------- CRF: gold score + forward algorithm, out[b] = logZ - total ----------------
__global__ __launch_bounds__(128) void k_crf(const float* __restrict__ emit,
    const int* __restrict__ tags, const int* __restrict__ lengths,
    const float* __restrict__ trans, float* __restrict__ out) {
  __shared__ float d_lds[8][17];
  __shared__ float tot[8][17];
  __shared__ float totb[8];
  const int tid = threadIdx.x;
  const int b = tid >> 4, k = tid & 15;
  const int len = lengths[b];

  float part = 0.f;
  for (int t = k; t < 512; t += 16) {
    if (t < len) {
      int tg = tags[b * 512 + t];
      part += emit[((size_t)t * 8 + b) * 16 + tg];
      if (t >= 1) part += trans[tags[b * 512 + t - 1] * 16 + tg];
    }
  }
  tot[b][k] = part;

  float trc[16];
#pragma unroll
  for (int i = 0; i < 16; ++i) trc[i] = trans[i * 16 + k];
  d_lds[b][k] = emit[b * 16 + k];
  __syncthreads();
  if (k == 0) {
    float s = 0.f;
    for (int i = 0; i < 16; ++i) s += tot[b][i];
    totb[b] = s;
  }
  __syncthreads();

  for (int t = 1; t < 512; ++t) {
    float nd = 0.f;
    bool upd = (t < len);
    if (upd) {
      float mx = -3.0e38f;
      float v[16];
#pragma unroll
      for (int i = 0; i < 16; ++i) { v[i] = d_lds[b][i] + trc[i]; mx = fmaxf(mx, v[i]); }
      float s = 0.f;
#pragma unroll
      for (int i = 0; i < 16; ++i) s += __expf(v[i] - mx);
      nd = mx + __logf(s) + emit[((size_t)t * 8 + b) * 16 + k];
    }
    __syncthreads();
    if (upd) d_lds[b][k] = nd;
    __syncthreads();
  }

  if (k == 0) {
    float mx = -3.0e38f;
    for (int i = 0; i < 16; ++i) mx = fmaxf(mx, d_lds[b][i]);
    float s = 0.f;
    for (int i = 0; i < 16; ++i) s += __expf(d_lds[b][i] - mx);
    out[b] = (mx + __logf(s)) - totb[b];
  }
}

extern "C" void kernel_launch(void* const* d_in, const int* in_sizes, int n_in,
                              void* d_out, int out_size, void* d_ws, size_t ws_size,
                              hipStream_t stream) {
  const float* x       = (const float*)d_in[0];
  const int*   tags    = (const int*)d_in[1];
  const int*   lengths = (const int*)d_in[2];
  const float* W_ih_f  = (const float*)d_in[3];
  const float* W_hh_f  = (const float*)d_in[4];
  const float* b_f     = (const float*)d_in[5];
  const float* W_ih_b  = (const float*)d_in[6];
  const float* W_hh_b  = (const float*)d_in[7];
  const float* b_b     = (const float*)d_in[8];
  const float* W_emit  = (const float*)d_in[9];
  const float* b_emit  = (const float*)d_in[10];
  const float* trans   = (const float*)d_in[11];
  float* out = (float*)d_out;
  (void)in_sizes; (void)n_in; (void)out_size; (void)ws_size;

  char* ws = (char*)d_ws;
  unsigned short* A    = (unsigned short*)ws; ws += 16777216;   // 2 x 4096 x 1024 bf16
  unsigned short* Wp   = (unsigned short*)ws; ws += 16777216;   // 2 x 4096 x 1024 bf16
  unsigned short* WF   = (unsigned short*)ws; ws += 16777216;   // MFMA-frag-ordered W_hh
  unsigned short* P    = (unsigned short*)ws; ws += 67108864;   // 2 x 4096 x 4096 bf16
  float* h_seq = (float*)ws; ws += 33554432;                    // 2 x 512 x 8 x 1024 f32
  uint* hg     = (uint*)ws;  ws += 65536;                       // 2buf x 2dir x 8 x 512 u32
  uint* flags  = (uint*)ws;  ws += 4096;                        // [2][128] + pad
  float* emit  = (float*)ws; ws += 262144;
  float* WET   = (float*)ws; ws += 131072;

  static int attr_done = 0;
  if (!attr_done) {
    hipFuncSetAttribute((const void*)k_rec,
                        hipFuncAttributeMaxDynamicSharedMemorySize, 100736);
    attr_done = 1;
  }

  hipMemsetAsync(flags, 0, 4096, stream);
  k_build_A<<<8192, 256, 0, stream>>>(x, lengths, A);
  k_cast_wih<<<8192, 256, 0, stream>>>(W_ih_f, W_ih_b, Wp);
  k_build_wf<<<4096, 256, 0, stream>>>(W_hh_f, W_hh_b, WF);
  k_build_wet<<<128, 256, 0, stream>>>(W_emit, WET);
  k_proj<<<dim3(32, 32, 2), 256, 0, stream>>>(A, Wp, b_f, b_b, P);

  {
    const unsigned short* wf = WF;
    const unsigned short* pp = P;
    const int* ll = lengths;
    uint* hgp = hg; uint* fl = flags; float* hs = h_seq;
    void* args[] = { &wf, &pp, &ll, &hgp, &fl, &hs };
    hipLaunchCooperativeKernel((const void*)k_rec, dim3(256), dim3(256),
                               args, 100736, stream);
  }

  k_emit<<<1024, 64, 0, stream>>>(h_seq, WET, b_emit, lengths, emit);
  k_crf<<<1, 128, 0, stream>>>(emit, tags, lengths, trans, out);
}